// Round 11
// baseline (417.976 us; speedup 1.0000x reference)
//
#include <hip/hip_runtime.h>
#include <hip/hip_cooperative_groups.h>

namespace cg = cooperative_groups;

// GCN 3-layer: out = GCNconv3(relu(GCNconv2(relu(GCNconv1(x)))))
//
// R21 = R15 inner loops (binning bodies, scalar-k GEMM, agg -- all byte-
// proven 267us class) with the 4-kernel binning chain MERGED into one
// cooperative kernel (grid.sync between phases). Dispatches 10 -> 7.
// Rationale: bottom-up accounting of 267us = agg ~135 + binning ~20 +
// gemm ~25 -> ~87us residual over 10 dispatches = ~8-9us/dispatch launch
// overhead. Inner loops are closed (R10-R18: agg at per-edge floor;
// R20: k-blocked GEMM +26us -> reverted). Dispatch count is the lever.
// R16 lesson: no global atomics (fabric write-through).
//
//   P1. count: per-tile 256-bin LDS histogram -> cnt[bin][tile]   (391 blk)
//   P2. scan: per-bin exclusive scan over tiles (blocks 0..255)
//   P3. scatter: LDS sort per 4096-edge tile -> binned at precomputed base
//   P4. group: per-bin counting sort -> CSR {src*128, ew} + deg/dinv
//   C.  per layer: fp32 GEMM (R15 scalar-k) -> bf16 Y[r,64] = dinv*(X@W)
//   D.  agg (R15): 8 edges/VMEM gather, bpermute distribution,
//       out = dinv[d]*(sum_e ew*Y[s] + Y[d]) + b

#define TILE 4096
#define BCAP_MAX 9216   // per-bin capacity; bin load ~Binom mean 8163 sd 90

static __device__ __forceinline__ float4 f4zero() { return make_float4(0.f, 0.f, 0.f, 0.f); }

static __device__ __forceinline__ unsigned short f2bf_rne(float x) {
    unsigned u = __float_as_uint(x);
    u += 0x7FFFu + ((u >> 16) & 1u);     // round-to-nearest-even
    return (unsigned short)(u >> 16);
}
static __device__ __forceinline__ float bflo(unsigned u) { return __uint_as_float(u << 16); }
static __device__ __forceinline__ float bfhi(unsigned u) { return __uint_as_float(u & 0xffff0000u); }

// ---------------- Fused binning: count -> scan -> scatter -> group ---------
// 391 blocks x 1024 threads, cooperative. LDS = 76KB union -> 2 blk/CU,
// co-residency 512 >= 391. Phase bodies are the byte-proven R15 kernels.
__global__ __launch_bounds__(1024, 8) void bin_fused_kernel(
        const int* __restrict__ src, const int* __restrict__ dst,
        const float* __restrict__ ew, int* __restrict__ cntbase,
        int* __restrict__ bintotal, int2* __restrict__ binned,
        int* __restrict__ row_start, int* __restrict__ row_cnt,
        float* __restrict__ dinv, int E, int N, int bcap, int ntiles, int nbins) {
    __shared__ __align__(16) char sm[77824];
    const int tid = threadIdx.x;
    const int blk = blockIdx.x;
    cg::grid_group grid = cg::this_grid();

    // ---- P1: count (block = tile) ----
    {
        int* h = (int*)sm;
        if (tid < 256) h[tid] = 0;
        __syncthreads();
        const int e0 = blk * TILE;
        #pragma unroll
        for (int j = 0; j < 4; ++j) {
            int e = e0 + j * 1024 + tid;
            if (e < E) atomicAdd(&h[dst[e] >> 8], 1);
        }
        __syncthreads();
        if (tid < 256) cntbase[tid * ntiles + blk] = h[tid];
    }
    grid.sync();

    // ---- P2: scan (blocks 0..255 = bins; threads < 512 active) ----
    if (blk < 256) {
        int* buf = (int*)sm;
        int v = 0;
        if (tid < 512) {
            v = (tid < ntiles) ? cntbase[blk * ntiles + tid] : 0;
            buf[tid] = v;
        }
        __syncthreads();
        for (int off = 1; off < 512; off <<= 1) {   // inclusive Hillis-Steele
            int x = 0, a = 0;
            if (tid < 512) { x = buf[tid]; a = (tid >= off) ? buf[tid - off] : 0; }
            __syncthreads();
            if (tid < 512) buf[tid] = x + a;
            __syncthreads();
        }
        if (tid < ntiles) cntbase[blk * ntiles + tid] = buf[tid] - v;  // excl base
        if (tid == 0) bintotal[blk] = buf[511];
    }
    grid.sync();

    // ---- P3: scatter (block = tile) ----
    {
        int*  cnt   = (int*)sm;                       //  256 x4
        int*  scan  = (int*)(sm + 1024);              //  256 x4
        int*  gbase = (int*)(sm + 2048);              //  256 x4
        int2* sorted = (int2*)(sm + 3072);            // 4096 x8
        unsigned char* binof = (unsigned char*)(sm + 3072 + 32768);  // 4096

        if (tid < 256) cnt[tid] = 0;
        __syncthreads();

        int mypk[4]; float myew[4]; int mybin[4]; int myrank[4]; bool myok[4];
        const int e0 = blk * TILE;
        #pragma unroll
        for (int j = 0; j < 4; ++j) {
            int e = e0 + j * 1024 + tid;
            myok[j] = (e < E);
            if (myok[j]) {
                int d = dst[e];
                int s = src[e];
                myew[j]   = ew[e];
                mybin[j]  = d >> 8;
                mypk[j]   = (s << 8) | (d & 255);     // src:24b | dst_local:8b
                myrank[j] = atomicAdd(&cnt[mybin[j]], 1);
            }
        }
        __syncthreads();
        if (tid < 256) scan[tid] = cnt[tid];
        __syncthreads();
        for (int off = 1; off < 256; off <<= 1) {     // inclusive Hillis-Steele
            int v = 0;
            if (tid < 256) { v = scan[tid]; if (tid >= off) v += scan[tid - off]; }
            __syncthreads();
            if (tid < 256) scan[tid] = v;
            __syncthreads();
        }
        if (tid < 256) gbase[tid] = cntbase[tid * ntiles + blk];   // no atomics
        __syncthreads();
        #pragma unroll
        for (int j = 0; j < 4; ++j) {
            if (myok[j]) {
                int b = mybin[j];
                int slot = (scan[b] - cnt[b]) + myrank[j];   // excl prefix + rank
                sorted[slot] = make_int2(mypk[j], __float_as_int(myew[j]));
                binof[slot]  = (unsigned char)b;
            }
        }
        __syncthreads();
        const int total = scan[255];
        for (int i = tid; i < total; i += 1024) {
            int b = binof[i];
            int pos = gbase[b] + (i - (scan[b] - cnt[b]));
            if (pos < bcap)   // statistically unreachable; prevents OOB
                binned[(size_t)b * bcap + pos] = sorted[i];
        }
    }
    grid.sync();

    // ---- P4: group (blocks 0..nbins-1 = bins) ----
    if (blk < nbins) {
        int*   cntl = (int*)sm;                      //  256 x4
        float* degl = (float*)(sm + 1024);           //  256 x4
        int*   scan = (int*)(sm + 2048);             //  256 x4
        int*   run  = (int*)(sm + 3072);             //  256 x4
        int2*  sorted = (int2*)(sm + 4096);          // 9216 x8 = 73728

        int n = bintotal[blk];
        if (n > bcap) n = bcap;
        if (tid < 256) { cntl[tid] = 0; degl[tid] = 0.f; }
        __syncthreads();

        int2* seg = binned + (size_t)blk * bcap;
        for (int i = tid; i < n; i += 1024) {
            int2 v = seg[i];
            int dl = v.x & 255;
            atomicAdd(&cntl[dl], 1);
            atomicAdd(&degl[dl], __int_as_float(v.y));
        }
        __syncthreads();
        if (tid < 256) scan[tid] = cntl[tid];
        __syncthreads();
        for (int off = 1; off < 256; off <<= 1) {
            int v = 0;
            if (tid < 256) { v = scan[tid]; if (tid >= off) v += scan[tid - off]; }
            __syncthreads();
            if (tid < 256) scan[tid] = v;
            __syncthreads();
        }
        if (tid < 256) {
            int ex = scan[tid] - cntl[tid];
            int d = (blk << 8) + tid;
            if (d < N) {
                row_start[d] = blk * bcap + ex;
                row_cnt[d]   = cntl[tid];
                dinv[d]      = rsqrtf(degl[tid] + 1.0f);
            }
            run[tid] = ex;
        }
        __syncthreads();
        for (int i = tid; i < n; i += 1024) {
            int2 v = seg[i];
            int dl = v.x & 255;
            int r = atomicAdd(&run[dl], 1);
            sorted[r] = make_int2((v.x >> 8) << 7, v.y);   // {src*128, ew}
        }
        __syncthreads();
        for (int i = tid; i < n; i += 1024)          // in-place: reads done above
            seg[i] = sorted[i];
    }
}

// --- GEMM (R15 scalar-k, byte-proven): Y[r, stride 64](bf16) ---------------
template <int K, int M>
__global__ __launch_bounds__(256) void gemm_kernel(const float* __restrict__ X,
        const float* __restrict__ W, const float* __restrict__ dinv,
        unsigned short* __restrict__ Y, int N) {
    constexpr int KP = K + 4;
    __shared__ float xs[64 * KP];
    __shared__ float ws[K * M];
    const int tid = threadIdx.x;
    const int row0 = blockIdx.x * 64;

    for (int i = tid * 4; i < K * M; i += 1024)
        *(float4*)&ws[i] = *(const float4*)&W[i];

    const int nrows = min(64, N - row0);
    for (int i = tid * 4; i < 64 * K; i += 1024) {
        int r = i / K, k = i % K;
        float4 v = f4zero();
        if (r < nrows) v = *(const float4*)&X[(size_t)(row0 + r) * K + k];
        *(float4*)&xs[r * KP + k] = v;
    }
    __syncthreads();

    const int ct = tid & 15, rt = tid >> 4;
    const int c = ct * 4;
    const bool cok = (c < M);
    float acc[4][4] = {};
    for (int k = 0; k < K; ++k) {
        float a0 = xs[(rt +  0) * KP + k];
        float a1 = xs[(rt + 16) * KP + k];
        float a2 = xs[(rt + 32) * KP + k];
        float a3 = xs[(rt + 48) * KP + k];
        float4 bv = cok ? *(const float4*)&ws[k * M + c] : f4zero();
        acc[0][0] += a0 * bv.x; acc[0][1] += a0 * bv.y; acc[0][2] += a0 * bv.z; acc[0][3] += a0 * bv.w;
        acc[1][0] += a1 * bv.x; acc[1][1] += a1 * bv.y; acc[1][2] += a1 * bv.z; acc[1][3] += a1 * bv.w;
        acc[2][0] += a2 * bv.x; acc[2][1] += a2 * bv.y; acc[2][2] += a2 * bv.z; acc[2][3] += a2 * bv.w;
        acc[3][0] += a3 * bv.x; acc[3][1] += a3 * bv.y; acc[3][2] += a3 * bv.z; acc[3][3] += a3 * bv.w;
    }
    if (cok) {
        #pragma unroll
        for (int i = 0; i < 4; ++i) {
            int r = row0 + rt + 16 * i;
            if (r < N) {
                float dd = dinv[r];
                ushort4 o;
                o.x = f2bf_rne(acc[i][0] * dd); o.y = f2bf_rne(acc[i][1] * dd);
                o.z = f2bf_rne(acc[i][2] * dd); o.w = f2bf_rne(acc[i][3] * dd);
                *(ushort4*)&Y[(size_t)r * 64 + c] = o;
            }
        }
    }
}

// ---------------- Aggregate (R15, byte-identical): bpermute distribution ---
// xw: bf16 rows, stride 64 elems (128B), dinv-prescaled. One wave per node.
// 64-edge blocks vector-loaded int2 (double-buffered). Per 8-edge step:
// lane L serves edge t*8+(L>>3); {off,w} via 2 ds_bpermute; one
// global_load_dwordx4 covers 8 rows (8 lanes x 16B each); 8 unpack+fmac.
// out = dinv[d]*(sum_e ew*xw[s] + xw[d]) + b.
template <int FOUT, bool RELU>
__global__ __launch_bounds__(256) void agg_kernel(
        const unsigned short* __restrict__ xw,
        const int2* __restrict__ csr, const int* __restrict__ row_start,
        const int* __restrict__ row_cnt, const float* __restrict__ dinv,
        const float* __restrict__ bias, float* __restrict__ out, int N) {
    int wid = (int)((blockIdx.x * blockDim.x + threadIdx.x) >> 6);
    int lane = threadIdx.x & 63;
    if (wid >= N) return;

    const int2* row = csr + row_start[wid];
    const int   cnt = row_cnt[wid];
    const char* xwb = (const char*)xw;

    const int g = lane >> 3;                           // edge slot in step
    const unsigned li16 = (unsigned)(lane & 7) * 16u;  // byte chunk in row
    const int g4 = g << 2;                             // bpermute byte base

    float acc[8] = {0.f, 0.f, 0.f, 0.f, 0.f, 0.f, 0.f, 0.f};

    // prime block 0
    int2 edA = make_int2(0, 0);
    if (lane < cnt) edA = row[lane];                   // min(cnt,64) via lane<64

    for (int base = 0; base < cnt; base += 64) {
        const int m = min(cnt - base, 64);
        // prefetch next 64-edge block (overlaps with current processing)
        int2 edN = make_int2(0, 0);
        const int nb = base + 64;
        if (nb < cnt) {
            if (lane < cnt - nb) edN = row[nb + lane];
        }
        int bidx = g4;
        #pragma unroll 2
        for (int t = 0; t * 8 < m; ++t, bidx += 32) {
            unsigned off = (unsigned)__builtin_amdgcn_ds_bpermute(bidx, edA.x);
            unsigned wu  = (unsigned)__builtin_amdgcn_ds_bpermute(bidx, edA.y);
            const bool valid = (t * 8 + g) < m;
            off = valid ? off : 0u;
            float wf = valid ? __uint_as_float(wu) : 0.f;
            uint4 rv = *(const uint4*)(xwb + (size_t)(off + li16));
            acc[0] = fmaf(wf, bflo(rv.x), acc[0]);
            acc[1] = fmaf(wf, bfhi(rv.x), acc[1]);
            acc[2] = fmaf(wf, bflo(rv.y), acc[2]);
            acc[3] = fmaf(wf, bfhi(rv.y), acc[3]);
            acc[4] = fmaf(wf, bflo(rv.z), acc[4]);
            acc[5] = fmaf(wf, bfhi(rv.z), acc[5]);
            acc[6] = fmaf(wf, bflo(rv.w), acc[6]);
            acc[7] = fmaf(wf, bfhi(rv.w), acc[7]);
        }
        edA = edN;
    }

    // reduce across the 8 edge groups (lanes with same li)
    #pragma unroll
    for (int o = 8; o <= 32; o <<= 1) {
        #pragma unroll
        for (int t = 0; t < 8; ++t)
            acc[t] += __shfl_xor(acc[t], o);
    }

    if (lane < FOUT / 8) {   // g==0 lanes; features f0..f0+7
        const int f0 = lane * 8;
        uint4 sr = *(const uint4*)(xwb + ((unsigned)wid * 128u + li16));
        float dd = dinv[wid];
        float4 bv0 = *(const float4*)&bias[f0];
        float4 bv1 = *(const float4*)&bias[f0 + 4];
        float r0 = dd * (acc[0] + bflo(sr.x)) + bv0.x;
        float r1 = dd * (acc[1] + bfhi(sr.x)) + bv0.y;
        float r2 = dd * (acc[2] + bflo(sr.y)) + bv0.z;
        float r3 = dd * (acc[3] + bfhi(sr.y)) + bv0.w;
        float r4 = dd * (acc[4] + bflo(sr.z)) + bv1.x;
        float r5 = dd * (acc[5] + bfhi(sr.z)) + bv1.y;
        float r6 = dd * (acc[6] + bflo(sr.w)) + bv1.z;
        float r7 = dd * (acc[7] + bfhi(sr.w)) + bv1.w;
        if (RELU) {
            r0 = fmaxf(r0, 0.f); r1 = fmaxf(r1, 0.f); r2 = fmaxf(r2, 0.f); r3 = fmaxf(r3, 0.f);
            r4 = fmaxf(r4, 0.f); r5 = fmaxf(r5, 0.f); r6 = fmaxf(r6, 0.f); r7 = fmaxf(r7, 0.f);
        }
        *(float4*)&out[(size_t)wid * FOUT + f0]     = make_float4(r0, r1, r2, r3);
        *(float4*)&out[(size_t)wid * FOUT + f0 + 4] = make_float4(r4, r5, r6, r7);
    }
}

static inline size_t ws_align(size_t x) { return (x + 255) & ~(size_t)255; }

extern "C" void kernel_launch(void* const* d_in, const int* in_sizes, int n_in,
                              void* d_out, int out_size, void* d_ws, size_t ws_size,
                              hipStream_t stream) {
    const float* x  = (const float*)d_in[0];
    const int*   ei = (const int*)d_in[1];
    const float* ew = (const float*)d_in[2];
    const float* W1 = (const float*)d_in[3];
    const float* b1 = (const float*)d_in[4];
    const float* W2 = (const float*)d_in[5];
    const float* b2 = (const float*)d_in[6];
    const float* W3 = (const float*)d_in[7];
    const float* b3 = (const float*)d_in[8];
    float* out = (float*)d_out;

    const int N = in_sizes[0] / 128;   // 50000
    const int E = in_sizes[1] / 2;     // 1600000
    const int* src = ei;
    const int* dst = ei + E;
    const int nbins = (N + 255) >> 8;         // 196
    const int ntiles = (E + TILE - 1) / TILE; // 391 (must be <= 512 for scan)

    char* p = (char*)d_ws;
    size_t off = 0;
    auto alloc = [&](size_t bytes) -> char* {
        char* q = p + off;
        off = ws_align(off + bytes);
        return q;
    };
    int*   row_start = (int*)  alloc((size_t)N * 4);
    int*   row_cnt   = (int*)  alloc((size_t)N * 4);
    float* dinv      = (float*)alloc((size_t)N * 4);
    int*   cntbase   = (int*)  alloc((size_t)256 * ntiles * 4);  // [bin][tile]
    int*   bintotal  = (int*)  alloc((size_t)256 * 4);
    unsigned short* xwbuf = (unsigned short*)alloc((size_t)N * 64 * 2);  // bf16, stride 64
    float* hbuf      = (float*)alloc((size_t)N * 64 * 4);                // fp32 h
    size_t remain = (ws_size > off) ? (ws_size - off) : 0;
    int bcap = (int)(remain / ((size_t)nbins * 8));
    if (bcap > BCAP_MAX) bcap = BCAP_MAX;
    int2* binned = (int2*)alloc((size_t)nbins * (size_t)bcap * 8);

    const int gb = (N + 63) / 64;           // 782 GEMM tiles
    const int ab = (N + 3) / 4;             // one wave per node

    {
        // cooperative fused binning: 391 blocks x 1024, 76KB LDS, 2 blk/CU
        int E_ = E, N_ = N, bcap_ = bcap, ntiles_ = ntiles, nbins_ = nbins;
        const int* src_ = src; const int* dst_ = dst; const float* ew_ = ew;
        int* cntbase_ = cntbase; int* bintotal_ = bintotal; int2* binned_ = binned;
        int* row_start_ = row_start; int* row_cnt_ = row_cnt; float* dinv_ = dinv;
        void* args[] = { &src_, &dst_, &ew_, &cntbase_, &bintotal_, &binned_,
                         &row_start_, &row_cnt_, &dinv_, &E_, &N_, &bcap_,
                         &ntiles_, &nbins_ };
        hipLaunchCooperativeKernel((const void*)bin_fused_kernel,
                                   dim3(ntiles), dim3(1024), args, 0, stream);
    }

    gemm_kernel<128, 64><<<gb, 256, 0, stream>>>(x, W1, dinv, xwbuf, N);
    agg_kernel<64, true ><<<ab, 256, 0, stream>>>(xwbuf, binned, row_start, row_cnt, dinv, b1, hbuf, N);
    gemm_kernel<64, 64><<<gb, 256, 0, stream>>>(hbuf, W2, dinv, xwbuf, N);
    agg_kernel<64, true ><<<ab, 256, 0, stream>>>(xwbuf, binned, row_start, row_cnt, dinv, b2, hbuf, N);
    gemm_kernel<64, 40><<<gb, 256, 0, stream>>>(hbuf, W3, dinv, xwbuf, N);
    agg_kernel<40, false><<<ab, 256, 0, stream>>>(xwbuf, binned, row_start, row_cnt, dinv, b3, out, N);
}

// Round 12
// 268.154 us; speedup vs baseline: 1.5587x; 1.5587x over previous
//
#include <hip/hip_runtime.h>

// GCN 3-layer: out = GCNconv3(relu(GCNconv2(relu(GCNconv1(x)))))
//
// R22 = R15 binning + R15 agg (byte-proven 267us class) + no-LDS-W GEMM.
// R21 lessons: grid.sync = fabric-atomic spin (~50us/sync) -> cooperative
// fusion dead; binning chain + gaps = ~15us TOTAL -> launch overhead ~2-3us
// -> dispatch-count theory dead. Budget rework (R11 direct agg measurement:
// 6x45.6=273 of 383 total -> non-agg 110) pins GEMMs at ~20-25us each,
// 3-4x their ~6us VALU roofline. Cause: 66KB LDS (xs 34 + ws 32) -> 2
// blocks/CU -> 1.53 rounds (half-empty tail) + W-stage phase + 2nd barrier.
// Fix: W (32KB, fits L1) read directly from global -- ws LDS dropped ->
// 34KB LDS -> 4 blocks/CU -> single round, staging phase gone.
// Agg law (R10-R18): at per-edge floor, closed. R16: no global atomics.
//
//   A1. bin_count: per-tile 256-bin LDS histogram -> cnt[bin][tile]
//   A2. bin_scan: block per bin scans tile counts -> exclusive base + total
//   A3. bin_scatter: LDS sort per 4096-edge tile, flush to precomputed base
//   B.  bin_group: per-bin counting sort -> CSR {src*128, ew} + deg/dinv
//   C.  per layer: fp32 GEMM (W from L1/global) -> bf16 Y[r,64] = dinv*(X@W)
//   D.  agg (R15): 8 edges/VMEM gather, bpermute distribution,
//       out = dinv[d]*(sum_e ew*Y[s] + Y[d]) + b

#define TILE 4096
#define BCAP_MAX 9216   // per-bin capacity; bin load ~Binom mean 8163 sd 90

static __device__ __forceinline__ float4 f4zero() { return make_float4(0.f, 0.f, 0.f, 0.f); }

static __device__ __forceinline__ unsigned short f2bf_rne(float x) {
    unsigned u = __float_as_uint(x);
    u += 0x7FFFu + ((u >> 16) & 1u);     // round-to-nearest-even
    return (unsigned short)(u >> 16);
}
static __device__ __forceinline__ float bflo(unsigned u) { return __uint_as_float(u << 16); }
static __device__ __forceinline__ float bfhi(unsigned u) { return __uint_as_float(u & 0xffff0000u); }

// ---------------- A1: per-tile bin histogram -> cnt[bin][tile] -------------
__global__ __launch_bounds__(1024) void bin_count_kernel(
        const int* __restrict__ dst, int* __restrict__ cnt, int E, int ntiles) {
    __shared__ int h[256];
    const int tid = threadIdx.x;
    const int t = blockIdx.x;
    if (tid < 256) h[tid] = 0;
    __syncthreads();
    const int e0 = t * TILE;
    #pragma unroll
    for (int j = 0; j < 4; ++j) {
        int e = e0 + j * 1024 + tid;
        if (e < E) atomicAdd(&h[dst[e] >> 8], 1);
    }
    __syncthreads();
    if (tid < 256) cnt[tid * ntiles + t] = h[tid];
}

// ---------------- A2: per-bin exclusive scan over tiles --------------------
__global__ __launch_bounds__(512) void bin_scan_kernel(
        int* __restrict__ cnt, int* __restrict__ bintotal, int ntiles) {
    __shared__ int buf[512];
    const int b = blockIdx.x;
    const int tid = threadIdx.x;
    int v = (tid < ntiles) ? cnt[b * ntiles + tid] : 0;
    buf[tid] = v;
    __syncthreads();
    for (int off = 1; off < 512; off <<= 1) {   // inclusive Hillis-Steele
        int x = buf[tid];
        int a = (tid >= off) ? buf[tid - off] : 0;
        __syncthreads();
        buf[tid] = x + a;
        __syncthreads();
    }
    if (tid < ntiles) cnt[b * ntiles + tid] = buf[tid] - v;   // exclusive base
    if (tid == 0) bintotal[b] = buf[511];
}

// ---------------- A3: tile-level LDS binning, deterministic flush ----------
__global__ __launch_bounds__(1024) void bin_scatter_kernel(
        const int* __restrict__ src, const int* __restrict__ dst,
        const float* __restrict__ ew, const int* __restrict__ cntbase,
        int2* __restrict__ binned, int E, int bcap, int ntiles) {
    __shared__ int cnt[256];
    __shared__ int scan[256];
    __shared__ int gbase[256];
    __shared__ int2 sorted[TILE];
    __shared__ unsigned char binof[TILE];
    const int tid = threadIdx.x;
    const int t = blockIdx.x;
    const int e0 = t * TILE;

    if (tid < 256) cnt[tid] = 0;
    __syncthreads();

    int mypk[4]; float myew[4]; int mybin[4]; int myrank[4]; bool myok[4];
    #pragma unroll
    for (int j = 0; j < 4; ++j) {
        int e = e0 + j * 1024 + tid;
        myok[j] = (e < E);
        if (myok[j]) {
            int d = dst[e];
            int s = src[e];
            myew[j]   = ew[e];
            mybin[j]  = d >> 8;
            mypk[j]   = (s << 8) | (d & 255);     // src:24b | dst_local:8b
            myrank[j] = atomicAdd(&cnt[mybin[j]], 1);
        }
    }
    __syncthreads();
    if (tid < 256) scan[tid] = cnt[tid];
    __syncthreads();
    for (int off = 1; off < 256; off <<= 1) {     // inclusive Hillis-Steele
        int v = 0;
        if (tid < 256) { v = scan[tid]; if (tid >= off) v += scan[tid - off]; }
        __syncthreads();
        if (tid < 256) scan[tid] = v;
        __syncthreads();
    }
    if (tid < 256) gbase[tid] = cntbase[tid * ntiles + t];   // no atomics
    __syncthreads();
    #pragma unroll
    for (int j = 0; j < 4; ++j) {
        if (myok[j]) {
            int b = mybin[j];
            int slot = (scan[b] - cnt[b]) + myrank[j];   // excl prefix + rank
            sorted[slot] = make_int2(mypk[j], __float_as_int(myew[j]));
            binof[slot]  = (unsigned char)b;
        }
    }
    __syncthreads();
    const int total = scan[255];
    for (int i = tid; i < total; i += 1024) {
        int b = binof[i];
        int pos = gbase[b] + (i - (scan[b] - cnt[b]));
        if (pos < bcap)   // statistically unreachable; prevents OOB
            binned[(size_t)b * bcap + pos] = sorted[i];
    }
}

// ---------------- B: per-bin counting sort -> CSR (+ deg/dinv) -------------
// Final CSR payload: {src*128 (row byte offset, stride-64 bf16 rows), ew}
__global__ __launch_bounds__(1024) void bin_group_kernel(
        int2* __restrict__ binned, const int* __restrict__ bintotal,
        int* __restrict__ row_start, int* __restrict__ row_cnt,
        float* __restrict__ dinv, int N, int bcap) {
    __shared__ int   cntl[256];
    __shared__ float degl[256];
    __shared__ int   scan[256];
    __shared__ int   run[256];
    __shared__ int2  sorted[BCAP_MAX];
    const int b = blockIdx.x;
    const int tid = threadIdx.x;
    int n = bintotal[b];
    if (n > bcap) n = bcap;
    if (tid < 256) { cntl[tid] = 0; degl[tid] = 0.f; }
    __syncthreads();

    int2* seg = binned + (size_t)b * bcap;
    for (int i = tid; i < n; i += 1024) {
        int2 v = seg[i];
        int dl = v.x & 255;
        atomicAdd(&cntl[dl], 1);
        atomicAdd(&degl[dl], __int_as_float(v.y));
    }
    __syncthreads();
    if (tid < 256) scan[tid] = cntl[tid];
    __syncthreads();
    for (int off = 1; off < 256; off <<= 1) {
        int v = 0;
        if (tid < 256) { v = scan[tid]; if (tid >= off) v += scan[tid - off]; }
        __syncthreads();
        if (tid < 256) scan[tid] = v;
        __syncthreads();
    }
    if (tid < 256) {
        int ex = scan[tid] - cntl[tid];
        int d = (b << 8) + tid;
        if (d < N) {
            row_start[d] = b * bcap + ex;
            row_cnt[d]   = cntl[tid];
            dinv[d]      = rsqrtf(degl[tid] + 1.0f);
        }
        run[tid] = ex;
    }
    __syncthreads();
    for (int i = tid; i < n; i += 1024) {
        int2 v = seg[i];
        int dl = v.x & 255;
        int r = atomicAdd(&run[dl], 1);
        sorted[r] = make_int2((v.x >> 8) << 7, v.y);   // {src*128, ew}
    }
    __syncthreads();
    for (int i = tid; i < n; i += 1024)          // in-place: reads done above
        seg[i] = sorted[i];
}

// --- GEMM (R22): Y[r, stride 64](bf16) = dinv[r]*(X@W), W from L1/global ---
// xs-only LDS (33.8KB) -> 4 blocks/CU -> 782 blocks in ONE round; no W-stage
// phase, no second barrier. W (<=32KB) is L1-resident; per iter each wave
// reads 256B contiguous of W (4 lanes share each 16B address).
template <int K, int M>
__global__ __launch_bounds__(256) void gemm_kernel(const float* __restrict__ X,
        const float* __restrict__ W, const float* __restrict__ dinv,
        unsigned short* __restrict__ Y, int N) {
    constexpr int KP = K + 4;
    __shared__ float xs[64 * KP];
    const int tid = threadIdx.x;
    const int row0 = blockIdx.x * 64;

    const int nrows = min(64, N - row0);
    for (int i = tid * 4; i < 64 * K; i += 1024) {
        int r = i / K, k = i % K;
        float4 v = f4zero();
        if (r < nrows) v = *(const float4*)&X[(size_t)(row0 + r) * K + k];
        *(float4*)&xs[r * KP + k] = v;
    }
    __syncthreads();

    const int ct = tid & 15, rt = tid >> 4;
    const int c = ct * 4;
    const bool cok = (c < M);
    float acc[4][4] = {};
    for (int k = 0; k < K; ++k) {
        float a0 = xs[(rt +  0) * KP + k];
        float a1 = xs[(rt + 16) * KP + k];
        float a2 = xs[(rt + 32) * KP + k];
        float a3 = xs[(rt + 48) * KP + k];
        float4 bv = cok ? *(const float4*)&W[k * M + c] : f4zero();
        acc[0][0] += a0 * bv.x; acc[0][1] += a0 * bv.y; acc[0][2] += a0 * bv.z; acc[0][3] += a0 * bv.w;
        acc[1][0] += a1 * bv.x; acc[1][1] += a1 * bv.y; acc[1][2] += a1 * bv.z; acc[1][3] += a1 * bv.w;
        acc[2][0] += a2 * bv.x; acc[2][1] += a2 * bv.y; acc[2][2] += a2 * bv.z; acc[2][3] += a2 * bv.w;
        acc[3][0] += a3 * bv.x; acc[3][1] += a3 * bv.y; acc[3][2] += a3 * bv.z; acc[3][3] += a3 * bv.w;
    }
    if (cok) {
        #pragma unroll
        for (int i = 0; i < 4; ++i) {
            int r = row0 + rt + 16 * i;
            if (r < N) {
                float dd = dinv[r];
                ushort4 o;
                o.x = f2bf_rne(acc[i][0] * dd); o.y = f2bf_rne(acc[i][1] * dd);
                o.z = f2bf_rne(acc[i][2] * dd); o.w = f2bf_rne(acc[i][3] * dd);
                *(ushort4*)&Y[(size_t)r * 64 + c] = o;
            }
        }
    }
}

// ---------------- Aggregate (R15, byte-identical): bpermute distribution ---
// xw: bf16 rows, stride 64 elems (128B), dinv-prescaled. One wave per node.
// 64-edge blocks vector-loaded int2 (double-buffered). Per 8-edge step:
// lane L serves edge t*8+(L>>3); {off,w} via 2 ds_bpermute; one
// global_load_dwordx4 covers 8 rows (8 lanes x 16B each); 8 unpack+fmac.
// out = dinv[d]*(sum_e ew*xw[s] + xw[d]) + b.
template <int FOUT, bool RELU>
__global__ __launch_bounds__(256) void agg_kernel(
        const unsigned short* __restrict__ xw,
        const int2* __restrict__ csr, const int* __restrict__ row_start,
        const int* __restrict__ row_cnt, const float* __restrict__ dinv,
        const float* __restrict__ bias, float* __restrict__ out, int N) {
    int wid = (int)((blockIdx.x * blockDim.x + threadIdx.x) >> 6);
    int lane = threadIdx.x & 63;
    if (wid >= N) return;

    const int2* row = csr + row_start[wid];
    const int   cnt = row_cnt[wid];
    const char* xwb = (const char*)xw;

    const int g = lane >> 3;                           // edge slot in step
    const unsigned li16 = (unsigned)(lane & 7) * 16u;  // byte chunk in row
    const int g4 = g << 2;                             // bpermute byte base

    float acc[8] = {0.f, 0.f, 0.f, 0.f, 0.f, 0.f, 0.f, 0.f};

    // prime block 0
    int2 edA = make_int2(0, 0);
    if (lane < cnt) edA = row[lane];                   // min(cnt,64) via lane<64

    for (int base = 0; base < cnt; base += 64) {
        const int m = min(cnt - base, 64);
        // prefetch next 64-edge block (overlaps with current processing)
        int2 edN = make_int2(0, 0);
        const int nb = base + 64;
        if (nb < cnt) {
            if (lane < cnt - nb) edN = row[nb + lane];
        }
        int bidx = g4;
        #pragma unroll 2
        for (int t = 0; t * 8 < m; ++t, bidx += 32) {
            unsigned off = (unsigned)__builtin_amdgcn_ds_bpermute(bidx, edA.x);
            unsigned wu  = (unsigned)__builtin_amdgcn_ds_bpermute(bidx, edA.y);
            const bool valid = (t * 8 + g) < m;
            off = valid ? off : 0u;
            float wf = valid ? __uint_as_float(wu) : 0.f;
            uint4 rv = *(const uint4*)(xwb + (size_t)(off + li16));
            acc[0] = fmaf(wf, bflo(rv.x), acc[0]);
            acc[1] = fmaf(wf, bfhi(rv.x), acc[1]);
            acc[2] = fmaf(wf, bflo(rv.y), acc[2]);
            acc[3] = fmaf(wf, bfhi(rv.y), acc[3]);
            acc[4] = fmaf(wf, bflo(rv.z), acc[4]);
            acc[5] = fmaf(wf, bfhi(rv.z), acc[5]);
            acc[6] = fmaf(wf, bflo(rv.w), acc[6]);
            acc[7] = fmaf(wf, bfhi(rv.w), acc[7]);
        }
        edA = edN;
    }

    // reduce across the 8 edge groups (lanes with same li)
    #pragma unroll
    for (int o = 8; o <= 32; o <<= 1) {
        #pragma unroll
        for (int t = 0; t < 8; ++t)
            acc[t] += __shfl_xor(acc[t], o);
    }

    if (lane < FOUT / 8) {   // g==0 lanes; features f0..f0+7
        const int f0 = lane * 8;
        uint4 sr = *(const uint4*)(xwb + ((unsigned)wid * 128u + li16));
        float dd = dinv[wid];
        float4 bv0 = *(const float4*)&bias[f0];
        float4 bv1 = *(const float4*)&bias[f0 + 4];
        float r0 = dd * (acc[0] + bflo(sr.x)) + bv0.x;
        float r1 = dd * (acc[1] + bfhi(sr.x)) + bv0.y;
        float r2 = dd * (acc[2] + bflo(sr.y)) + bv0.z;
        float r3 = dd * (acc[3] + bfhi(sr.y)) + bv0.w;
        float r4 = dd * (acc[4] + bflo(sr.z)) + bv1.x;
        float r5 = dd * (acc[5] + bfhi(sr.z)) + bv1.y;
        float r6 = dd * (acc[6] + bflo(sr.w)) + bv1.z;
        float r7 = dd * (acc[7] + bfhi(sr.w)) + bv1.w;
        if (RELU) {
            r0 = fmaxf(r0, 0.f); r1 = fmaxf(r1, 0.f); r2 = fmaxf(r2, 0.f); r3 = fmaxf(r3, 0.f);
            r4 = fmaxf(r4, 0.f); r5 = fmaxf(r5, 0.f); r6 = fmaxf(r6, 0.f); r7 = fmaxf(r7, 0.f);
        }
        *(float4*)&out[(size_t)wid * FOUT + f0]     = make_float4(r0, r1, r2, r3);
        *(float4*)&out[(size_t)wid * FOUT + f0 + 4] = make_float4(r4, r5, r6, r7);
    }
}

static inline size_t ws_align(size_t x) { return (x + 255) & ~(size_t)255; }

extern "C" void kernel_launch(void* const* d_in, const int* in_sizes, int n_in,
                              void* d_out, int out_size, void* d_ws, size_t ws_size,
                              hipStream_t stream) {
    const float* x  = (const float*)d_in[0];
    const int*   ei = (const int*)d_in[1];
    const float* ew = (const float*)d_in[2];
    const float* W1 = (const float*)d_in[3];
    const float* b1 = (const float*)d_in[4];
    const float* W2 = (const float*)d_in[5];
    const float* b2 = (const float*)d_in[6];
    const float* W3 = (const float*)d_in[7];
    const float* b3 = (const float*)d_in[8];
    float* out = (float*)d_out;

    const int N = in_sizes[0] / 128;   // 50000
    const int E = in_sizes[1] / 2;     // 1600000
    const int* src = ei;
    const int* dst = ei + E;
    const int nbins = (N + 255) >> 8;         // 196
    const int ntiles = (E + TILE - 1) / TILE; // 391 (must be <= 512 for scan)

    char* p = (char*)d_ws;
    size_t off = 0;
    auto alloc = [&](size_t bytes) -> char* {
        char* q = p + off;
        off = ws_align(off + bytes);
        return q;
    };
    int*   row_start = (int*)  alloc((size_t)N * 4);
    int*   row_cnt   = (int*)  alloc((size_t)N * 4);
    float* dinv      = (float*)alloc((size_t)N * 4);
    int*   cntbase   = (int*)  alloc((size_t)256 * ntiles * 4);  // [bin][tile]
    int*   bintotal  = (int*)  alloc((size_t)256 * 4);
    unsigned short* xwbuf = (unsigned short*)alloc((size_t)N * 64 * 2);  // bf16, stride 64
    float* hbuf      = (float*)alloc((size_t)N * 64 * 4);                // fp32 h
    size_t remain = (ws_size > off) ? (ws_size - off) : 0;
    int bcap = (int)(remain / ((size_t)nbins * 8));
    if (bcap > BCAP_MAX) bcap = BCAP_MAX;
    int2* binned = (int2*)alloc((size_t)nbins * (size_t)bcap * 8);

    const int gb = (N + 63) / 64;           // 782 GEMM tiles
    const int ab = (N + 3) / 4;             // one wave per node

    bin_count_kernel<<<ntiles, 1024, 0, stream>>>(dst, cntbase, E, ntiles);
    bin_scan_kernel<<<256, 512, 0, stream>>>(cntbase, bintotal, ntiles);
    bin_scatter_kernel<<<ntiles, 1024, 0, stream>>>(src, dst, ew, cntbase, binned, E, bcap, ntiles);
    bin_group_kernel<<<nbins, 1024, 0, stream>>>(binned, bintotal, row_start, row_cnt, dinv, N, bcap);

    gemm_kernel<128, 64><<<gb, 256, 0, stream>>>(x, W1, dinv, xwbuf, N);
    agg_kernel<64, true ><<<ab, 256, 0, stream>>>(xwbuf, binned, row_start, row_cnt, dinv, b1, hbuf, N);
    gemm_kernel<64, 64><<<gb, 256, 0, stream>>>(hbuf, W2, dinv, xwbuf, N);
    agg_kernel<64, true ><<<ab, 256, 0, stream>>>(xwbuf, binned, row_start, row_cnt, dinv, b2, hbuf, N);
    gemm_kernel<64, 40><<<gb, 256, 0, stream>>>(hbuf, W3, dinv, xwbuf, N);
    agg_kernel<40, false><<<ab, 256, 0, stream>>>(xwbuf, binned, row_start, row_cnt, dinv, b3, out, N);
}